// Round 19
// baseline (207.513 us; speedup 1.0000x reference)
//
#include <hip/hip_runtime.h>

#define DEVI __device__ __forceinline__

typedef __bf16 v8bf __attribute__((ext_vector_type(8)));
typedef float f32x4 __attribute__((ext_vector_type(4)));
typedef int int4v __attribute__((ext_vector_type(4)));
typedef int int2v __attribute__((ext_vector_type(2)));

constexpr int B_  = 2;
constexpr int C_  = 96;
constexpr int IMG = 256;
constexpr int N_  = 16384;   // tokens
constexpr int TD  = 384;
constexpr int H_  = 6;
constexpr int G_  = 50;

DEVI short f2bf(float f){
  unsigned u = __builtin_bit_cast(unsigned, f);
  u = (u + 0x7fffu + ((u >> 16) & 1u)) >> 16;
  return (short)u;
}
DEVI unsigned cvtpk(float lo, float hi){   // dst[15:0]=bf16(lo), dst[31:16]=bf16(hi)
  unsigned r;
  asm("v_cvt_pk_bf16_f32 %0, %1, %2" : "=v"(r) : "v"(lo), "v"(hi));
  return r;
}
DEVI int gpos(int g){ return (16383 * g) / 49; }   // np.linspace(0,16383,50).astype(int32)

DEVI f32x4 mfma16(v8bf a, v8bf b, f32x4 c){
  return __builtin_amdgcn_mfma_f32_16x16x32_bf16(a, b, c, 0, 0, 0);
}

// async global->LDS, 16B per lane; LDS dest is wave-uniform base + lane*16
DEVI void gload16(const void* g, void* l){
  __builtin_amdgcn_global_load_lds((const __attribute__((address_space(1))) void*)g,
                                   (__attribute__((address_space(3))) void*)l, 16, 0, 0);
}

// ---------------- prep: W (k-major f32) -> Wt (n-major bf16) via LDS transpose ---
__global__ __launch_bounds__(256) void prep_w(
    const float* __restrict__ w0, const float* __restrict__ w1,
    const float* __restrict__ w2, const float* __restrict__ w3,
    const float* __restrict__ w4, const float* __restrict__ w5,
    short* __restrict__ Wt){
  __shared__ float sT[64][65];
  int z = blockIdx.y;
  const float* W = z==0 ? w0 : z==1 ? w1 : z==2 ? w2 : z==3 ? w3 : z==4 ? w4 : w5;
  int tile = blockIdx.x;                       // 36 tiles
  int k0 = (tile / 6) * 64, n0 = (tile % 6) * 64;
  int t = threadIdx.x;
  int r = t >> 2, c0 = (t & 3) * 16;
  #pragma unroll
  for (int e = 0; e < 16; e += 4){
    f32x4 v = *reinterpret_cast<const f32x4*>(&W[(size_t)(k0+r)*TD + n0 + c0 + e]);
    #pragma unroll
    for (int i = 0; i < 4; i++) sT[r][c0 + e + i] = v[i];
  }
  __syncthreads();
  int rn = t >> 2, ck0 = (t & 3) * 16;
  short pk[16];
  #pragma unroll
  for (int e = 0; e < 16; e++) pk[e] = f2bf(sT[ck0 + e][rn]);
  short* dst = Wt + (size_t)z*TD*TD + (size_t)(n0+rn)*TD + k0 + ck0;
  *reinterpret_cast<int4v*>(dst)     = *reinterpret_cast<int4v*>(&pk[0]);
  *reinterpret_cast<int4v*>(dst + 8) = *reinterpret_cast<int4v*>(&pk[8]);
}

// ------- tokenize v2: LDS-staged, coalesced x reads ------------------------------
__global__ __launch_bounds__(256) void tokenize(const float* __restrict__ x,
                                                short* __restrict__ tokens){
  __shared__ float sX[24][2][260];
  int p = blockIdx.x, cq = blockIdx.y, b = blockIdx.z;
  int tid = threadIdx.x;
  #pragma unroll
  for (int it = 0; it < 12; it++){
    int u = it*256 + tid;
    int c_l = u >> 7, rem = u & 127, r = rem >> 6, j4 = rem & 63;
    f32x4 v = *reinterpret_cast<const f32x4*>(
        &x[(((size_t)b*C_ + cq*24 + c_l)*IMG + 2*p + r)*IMG + j4*4]);
    *reinterpret_cast<f32x4*>(&sX[c_l][r][j4*4]) = v;
  }
  __syncthreads();
  #pragma unroll
  for (int it = 0; it < 6; it++){
    int v = it*256 + tid;
    int nsj = v / 12, ck = v % 12;
    short o[8];
    #pragma unroll
    for (int e = 0; e < 8; e++){
      int tl = ck*8 + e;
      int c_l = tl >> 2, wi = (tl >> 1) & 1, wj = tl & 1;
      o[e] = f2bf(sX[c_l][wi][2*nsj + wj]);
    }
    *reinterpret_cast<int4v*>(tokens + ((size_t)b*N_ + p*128 + nsj)*TD + cq*96 + ck*8)
        = *reinterpret_cast<int4v*>(o);
  }
}

// ------- 6-way projection GEMM: 128x128, BK=32 dbuf, counted-vmcnt pipeline ------
__global__ __launch_bounds__(256) void gemm_proj(
    const short* __restrict__ A, const short* __restrict__ Wt,
    const float* __restrict__ bq, const float* __restrict__ bk, const float* __restrict__ bv,
    const float* __restrict__ bkg, const float* __restrict__ bvg, const float* __restrict__ bqg,
    short* __restrict__ qbuf, short* __restrict__ kbuf, short* __restrict__ vT,
    short* __restrict__ kgabuf, short* __restrict__ vgaT, short* __restrict__ qgb)
{
  __shared__ short smem[16384];                 // [0,8K): sA dbuf, [8K,16K): sB dbuf
  int lin = blockIdx.x;
  int mt, by, bz;
  if (lin < 3840){
    int id = (lin & 7)*480 + (lin >> 3);
    mt = id / 15; int r15 = id % 15;
    by = r15 % 3; bz = r15 / 3;
  } else {
    int id2 = lin - 3840;
    if (id2 >= 3) return;
    mt = 0; by = id2; bz = 5;
  }
  const float* bias = bz==0 ? bq : bz==1 ? bk : bz==2 ? bv : bz==3 ? bkg : bz==4 ? bvg : bqg;
  const short* Wz = Wt + bz*TD*TD;
  int m0 = mt * 128, n0 = by * 128;
  int tid = threadIdx.x, l = tid & 63, w = tid >> 6;
  int wm = w >> 1, wn = w & 1;
  int q16 = l & 15, g4 = l >> 4;
  bool trans = (bz == 2 || bz == 4);
  bool is_qg = (bz == 5);

  int st_r  = (l >> 2);
  int st_cg = ((l & 3) ^ ((l >> 3) & 3));
  auto STAGE = [&](int kt, int s){
    #pragma unroll
    for (int it = 0; it < 4; it++){
      int ch = w*4 + it;
      int c8 = ch & 7;
      int r_ = c8*16 + st_r;
      const short* src;
      if (ch < 8){
        const short* abase;
        if (is_qg){
          int bq_ = r_ >> 6, qq = r_ & 63;
          abase = A + ((size_t)bq_*N_ + gpos(qq < G_ ? qq : 0))*TD;
        } else {
          abase = A + (size_t)(m0+r_)*TD;
        }
        src = abase + kt*32 + st_cg*8;
      } else {
        src = Wz + (size_t)(n0+r_)*TD + kt*32 + st_cg*8;
      }
      gload16(src, smem + ((ch < 8) ? 0 : 8192) + s*4096 + c8*512);
    }
  };

  int fr = q16;
  int fcg = g4 ^ ((l >> 1) & 3);
  f32x4 acc[4][4] = {};

  STAGE(0, 0);
  if (trans){
    #pragma unroll 2
    for (int t = 0; t < 12; t++){
      int cur = t & 1;
      if (t < 11){ STAGE(t+1, cur ^ 1); asm volatile("s_waitcnt vmcnt(4)" ::: "memory"); }
      else       { asm volatile("s_waitcnt vmcnt(0)" ::: "memory"); }
      __builtin_amdgcn_s_barrier();
      v8bf af[4], bfr[4];
      #pragma unroll
      for (int i = 0; i < 4; i++){
        af[i]  = *reinterpret_cast<const v8bf*>(&smem[       cur*4096 + (wm*64 + i*16 + fr)*32 + fcg*8]);
        bfr[i] = *reinterpret_cast<const v8bf*>(&smem[8192 + cur*4096 + (wn*64 + i*16 + fr)*32 + fcg*8]);
      }
      #pragma unroll
      for (int mi = 0; mi < 4; mi++)
        #pragma unroll
        for (int ni = 0; ni < 4; ni++)
          acc[mi][ni] = mfma16(af[mi], bfr[ni], acc[mi][ni]);
      asm volatile("s_waitcnt lgkmcnt(0)" ::: "memory");
      __builtin_amdgcn_s_barrier();
    }
    // transpose epilogue -> vT/vgaT [bh][64 d][N n]
    short* outT = (bz == 2) ? vT : vgaT;
    #pragma unroll
    for (int mi = 0; mi < 4; mi++){
      int n_base = wm*64 + mi*16 + g4*4;
      #pragma unroll
      for (int ni = 0; ni < 4; ni++){
        int t_local = wn*64 + ni*16 + q16;
        float bc = bias[n0 + t_local];
        short pk[4];
        #pragma unroll
        for (int jj = 0; jj < 4; jj++) pk[jj] = f2bf(acc[mi][ni][jj] + bc);
        int phys = t_local*128 + (((n_base >> 3) ^ (t_local & 15)) << 3) + (n_base & 7);
        *reinterpret_cast<int2v*>(&smem[phys]) = *reinterpret_cast<int2v*>(pk);
      }
    }
    __syncthreads();
    int b = mt >> 7;
    int nb = m0 & 16383;
    #pragma unroll
    for (int p = 0; p < 8; p++){
      int t = p*16 + (tid >> 4);
      int c8 = tid & 15;
      int4v val = *reinterpret_cast<const int4v*>(&smem[t*128 + ((c8 ^ (t & 15)) << 3)]);
      int h = (n0 + t) >> 6, d = (n0 + t) & 63;
      *reinterpret_cast<int4v*>(outT + ((size_t)((b*H_ + h)*64 + d))*N_ + nb + c8*8) = val;
    }
  } else {
    // swapped-operand loop: acc[mi][ni][jj] = C[token mi-blk + q16][td ni-blk + g4*4+jj]
    #pragma unroll 2
    for (int t = 0; t < 12; t++){
      int cur = t & 1;
      if (t < 11){ STAGE(t+1, cur ^ 1); asm volatile("s_waitcnt vmcnt(4)" ::: "memory"); }
      else       { asm volatile("s_waitcnt vmcnt(0)" ::: "memory"); }
      __builtin_amdgcn_s_barrier();
      v8bf af[4], bfr[4];
      #pragma unroll
      for (int i = 0; i < 4; i++){
        af[i]  = *reinterpret_cast<const v8bf*>(&smem[       cur*4096 + (wm*64 + i*16 + fr)*32 + fcg*8]);
        bfr[i] = *reinterpret_cast<const v8bf*>(&smem[8192 + cur*4096 + (wn*64 + i*16 + fr)*32 + fcg*8]);
      }
      #pragma unroll
      for (int mi = 0; mi < 4; mi++)
        #pragma unroll
        for (int ni = 0; ni < 4; ni++)
          acc[mi][ni] = mfma16(bfr[ni], af[mi], acc[mi][ni]);
      asm volatile("s_waitcnt lgkmcnt(0)" ::: "memory");
      __builtin_amdgcn_s_barrier();
    }
    short* out = bz==0 ? qbuf : bz==1 ? kbuf : bz==3 ? kgabuf : qgb;
    float scale = (bz == 0 || bz == 5) ? 0.125f : 1.0f;
    // pack into smem [tok 128][td 128] with 8B-chunk XOR swizzle (2-way, free)
    #pragma unroll
    for (int mi = 0; mi < 4; mi++){
      int tl = wm*64 + mi*16 + q16;
      int x = (tl & 7) << 1;
      #pragma unroll
      for (int ni = 0; ni < 4; ni++){
        int tdl = wn*64 + ni*16 + g4*4;
        f32x4 bvv = *reinterpret_cast<const f32x4*>(&bias[n0 + tdl]);
        short pk[4];
        #pragma unroll
        for (int jj = 0; jj < 4; jj++) pk[jj] = f2bf((acc[mi][ni][jj] + bvv[jj]) * scale);
        int c4 = (tdl >> 2) ^ x;
        *reinterpret_cast<int2v*>(&smem[tl*128 + c4*4]) = *reinterpret_cast<int2v*>(pk);
      }
    }
    __syncthreads();
    #pragma unroll
    for (int p = 0; p < 8; p++){
      int r = p*16 + (tid >> 4);
      int c16 = tid & 15;
      int c4 = (2*c16) ^ ((r & 7) << 1);
      int4v val = *reinterpret_cast<const int4v*>(&smem[r*128 + c4*4]);
      *reinterpret_cast<int4v*>(out + (size_t)(m0 + r)*TD + n0 + c16*8) = val;
    }
  }
}

// ------- per-bh gather of global-token K rows and V^T cols (widened grid) --------
__global__ void gather_gkv(const short* __restrict__ kbuf, const short* __restrict__ vT,
                           short* __restrict__ kg, short* __restrict__ vgTg){
  int bh = blockIdx.x; int s = blockIdx.y;
  int b = bh / H_, h = bh % H_;
  int t = threadIdx.x;
  {                                            // vgTg[bh][64 d][64 g], d-slice
    int d = s*4 + (t >> 6), g = t & 63;
    short val = 0;
    if (g < G_) val = vT[((size_t)bh*64 + d)*N_ + gpos(g)];
    vgTg[(size_t)bh*4096 + d*64 + g] = val;
  }
  {                                            // kg[bh][64 g][64 c], g-slice
    int g = s*4 + (t >> 6), c = t & 63;
    short val = 0;
    if (g < G_) val = kbuf[((size_t)b*N_ + gpos(g))*TD + h*64 + c];
    kg[(size_t)bh*4096 + g*64 + c] = val;
  }
}

// ---- fused attention kernel: blocks 0..191 = gattn split-K partials (FIRST so ---
// ---- they overlap the band wave); blocks 192..1727 = band attention (R12) -------
__global__ __launch_bounds__(512, 4) void band_attn(
    const short* __restrict__ qb, const short* __restrict__ kbuf, const short* __restrict__ vT,
    const short* __restrict__ kg, const short* __restrict__ vgTg,
    const short* __restrict__ qgb, const short* __restrict__ kga, const short* __restrict__ vgaT,
    float* __restrict__ gpart, float* __restrict__ out)
{
  __shared__ short sK[448][64];    // band: K tiles | gattn: per-wave P regions
  __shared__ short sP[8][16][72];  // band: per-wave P[q][kk]
  int lin = blockIdx.x;
  int tid = threadIdx.x, l = tid & 63, w = tid >> 6;
  int g4 = l >> 4, q16 = l & 15;

  if (lin < 192){
    // ---------------- fused gattn_partial (q-split: 2 waves per record) ----------
    int gb = lin;
    int bh2 = gb >> 4, kcg = gb & 15;
    int b2 = bh2 / H_, h2 = bh2 % H_;
    int wr = w >> 1, qh = w & 1;
    int rec = kcg*4 + wr;                      // 0..63 per bh
    short* sp2 = &sK[0][0] + w*2304;           // [32 rows][72 cols] per wave
    v8bf aq2[2][2];
    #pragma unroll
    for (int rf2 = 0; rf2 < 2; rf2++)
      #pragma unroll
      for (int s = 0; s < 2; s++)
        aq2[rf2][s] = *reinterpret_cast<const v8bf*>(
            qgb + (b2*64 + (qh*2+rf2)*16 + q16)*TD + h2*64 + s*32 + g4*8);
    f32x4 o2[2][4] = {};
    float mr[2] = {-1e30f, -1e30f}, lr[2] = {0.f, 0.f};
    int keybase = rec*256;
    for (int st = 0; st < 4; st++){
      int key0 = keybase + st*64;
      v8bf bkf[4][2];
      #pragma unroll
      for (int kcf = 0; kcf < 4; kcf++)
        #pragma unroll
        for (int s = 0; s < 2; s++)
          bkf[kcf][s] = *reinterpret_cast<const v8bf*>(
              kga + ((size_t)b2*N_ + key0 + kcf*16 + q16)*TD + h2*64 + s*32 + g4*8);
      #pragma unroll
      for (int rf2 = 0; rf2 < 2; rf2++){
        f32x4 sc[4] = {};
        #pragma unroll
        for (int kcf = 0; kcf < 4; kcf++){
          sc[kcf] = mfma16(bkf[kcf][0], aq2[rf2][0], sc[kcf]);   // S^T[kk][q]
          sc[kcf] = mfma16(bkf[kcf][1], aq2[rf2][1], sc[kcf]);
        }
        float mk = -1e30f;
        #pragma unroll
        for (int kcf = 0; kcf < 4; kcf++)
          #pragma unroll
          for (int jj = 0; jj < 4; jj++) mk = fmaxf(mk, sc[kcf][jj]);
        mk = fmaxf(mk, __shfl_xor(mk, 16, 64));
        mk = fmaxf(mk, __shfl_xor(mk, 32, 64));
        float mnew = fmaxf(mr[rf2], mk);
        float f_ = __expf(mr[rf2] - mnew);
        mr[rf2] = mnew;
        float s_ = 0.f;
        #pragma unroll
        for (int kcf = 0; kcf < 4; kcf++){
          #pragma unroll
          for (int jj = 0; jj < 4; jj++){
            sc[kcf][jj] = __expf(sc[kcf][jj] - mnew);
            s_ += sc[kcf][jj];
          }
          int2v pw = { (int)cvtpk(sc[kcf][0], sc[kcf][1]), (int)cvtpk(sc[kcf][2], sc[kcf][3]) };
          *reinterpret_cast<int2v*>(&sp2[(rf2*16 + q16)*72 + kcf*16 + g4*4]) = pw;
        }
        s_ += __shfl_xor(s_, 16, 64);
        s_ += __shfl_xor(s_, 32, 64);
        lr[rf2] = lr[rf2]*f_ + s_;
        #pragma unroll
        for (int cf = 0; cf < 4; cf++)
          #pragma unroll
          for (int jj = 0; jj < 4; jj++) o2[rf2][cf][jj] *= f_;
      }
      v8bf bv[4][2];
      #pragma unroll
      for (int cf = 0; cf < 4; cf++)
        #pragma unroll
        for (int s2 = 0; s2 < 2; s2++)
          bv[cf][s2] = *reinterpret_cast<const v8bf*>(
              vgaT + ((size_t)bh2*64 + cf*16 + q16)*N_ + key0 + s2*32 + g4*8);
      #pragma unroll
      for (int rf2 = 0; rf2 < 2; rf2++){
        v8bf ap[2];
        #pragma unroll
        for (int s2 = 0; s2 < 2; s2++)
          ap[s2] = *reinterpret_cast<const v8bf*>(&sp2[(rf2*16 + q16)*72 + s2*32 + g4*8]);
        #pragma unroll
        for (int cf = 0; cf < 4; cf++){
          o2[rf2][cf] = mfma16(bv[cf][0], ap[0], o2[rf2][cf]);
          o2[rf2][cf] = mfma16(bv[cf][1], ap[1], o2[rf2][cf]);
        }
      }
    }
    float* base = gpart + (size_t)(bh2*64 + rec) * 4224;
    #pragma unroll
    for (int rf2 = 0; rf2 < 2; rf2++){
      int rf = qh*2 + rf2;
      if (g4 == 0){ base[rf*16 + q16] = mr[rf2]; base[64 + rf*16 + q16] = lr[rf2]; }
      #pragma unroll
      for (int cf = 0; cf < 4; cf++)
        #pragma unroll
        for (int jj = 0; jj < 4; jj++)
          base[128 + (cf*16 + g4*4 + jj)*64 + rf*16 + q16] = o2[rf2][cf][jj];
    }
    return;
  }

  // ---------------- band path (exact R12/R14 structure) --------------------------
  int lin2 = lin - 192;
  int id = (lin2 & 7)*192 + (lin2 >> 3);
  int c = id & 127;
  int bh = id >> 7; int b = bh / H_, h = bh % H_;
  int cb0 = c*128 - 128;

  #pragma unroll
  for (int it = 0; it < 7; it++){
    int ch = w*7 + it;
    int r = ch*8 + (l>>3);
    int cc = ((l & 7) ^ (l >> 3)) * 8;        // pre-swizzled source colgroup
    const short* src;
    if (ch < 8){
      src = kg + (size_t)bh*4096 + r*64 + cc;
    } else {
      int ka = cb0 + r - 64;
      ka = ka < 0 ? 0 : (ka > N_-1 ? N_-1 : ka);
      src = kbuf + ((size_t)b*N_ + ka)*TD + h*64 + cc;
    }
    gload16(src, &sK[ch*8][0]);
  }

  int qrow0 = c*128 + w*16;
  v8bf aq[2];
  #pragma unroll
  for (int s = 0; s < 2; s++)
    aq[s] = *reinterpret_cast<const v8bf*>(qb + ((size_t)b*N_ + qrow0 + q16)*TD + h*64 + s*32 + g4*8);

  __syncthreads();

  f32x4 o[4] = {};
  float mrun = -1e30f, lrun = 0.f;
  int sbase = w >> 2;
  int i_ = w*16 + q16;

  // QK^T of one 64-key sub-window from sK into sc[4] (swizzled read)
  auto QK = [&](int rbase, f32x4* sc){
    v8bf bkf[4][2];
    #pragma unroll
    for (int kc = 0; kc < 4; kc++)
      #pragma unroll
      for (int s = 0; s < 2; s++)
        bkf[kc][s] = *reinterpret_cast<const v8bf*>(
            &sK[rbase + kc*16 + q16][(((s << 2) | g4) ^ (q16 & 7)) * 8]);
    __builtin_amdgcn_s_setprio(1);
    #pragma unroll
    for (int kc = 0; kc < 4; kc++){
      sc[kc] = mfma16(bkf[kc][0], aq[0], sc[kc]);
      sc[kc] = mfma16(bkf[kc][1], aq[1], sc[kc]);
    }
    __builtin_amdgcn_s_setprio(0);
  };

  for (int ph = 0; ph < 3; ph++){
    int s0bA = (sbase + 2*ph - 1) * 64;     // ph=0: A = global keys
    int s0bB = (sbase + 2*ph) * 64;
    bool isgA = (ph == 0);
    int kabsA = cb0 + s0bA, kabsB = cb0 + s0bB;
    bool validA = isgA || (kabsA >= 0 && kabsA < N_);
    bool validB = (kabsB >= 0 && kabsB < N_);
    if (!validA && !validB) continue;

    f32x4 sc[8];
    const f32x4 negv = {-1e30f, -1e30f, -1e30f, -1e30f};
    #pragma unroll
    for (int j = 0; j < 8; j++) sc[j] = negv;

    if (validA){
      sc[0] = sc[1] = sc[2] = sc[3] = f32x4{0.f, 0.f, 0.f, 0.f};
      QK(isgA ? 0 : 64 + s0bA, &sc[0]);
      if (isgA){
        #pragma unroll
        for (int jj = 0; jj < 4; jj++)
          if (48 + g4*4 + jj >= G_) sc[3][jj] = -1e30f;
      } else {
        bool allv = (s0bA >= w*16 + 15) && (s0bA <= w*16 + 193);
        if (!allv){
          #pragma unroll
          for (int kc = 0; kc < 4; kc++)
            #pragma unroll
            for (int jj = 0; jj < 4; jj++){
              int rel = s0bA + kc*16 + g4*4 + jj - 128 - i_;
              if (rel < -128 || rel > 128) sc[kc][jj] = -1e30f;
            }
        }
      }
    }
    if (validB){
      sc[4] = sc[5] = sc[6] = sc[7] = f32x4{0.f, 0.f, 0.f, 0.f};
      QK(64 + s0bB, &sc[4]);
      bool allv = (s0bB >= w*16 + 15) && (s0bB <= w*16 + 193);
      if (!allv){
        #pragma unroll
        for (int kc = 0; kc < 4; kc++)
          #pragma unroll
          for (int jj = 0; jj < 4; jj++){
            int rel = s0bB + kc*16 + g4*4 + jj - 128 - i_;
            if (rel < -128 || rel > 128) sc[4+kc][jj] = -1e30f;
          }
      }
    }
    // one reduce + (deferred) rescale per 128 keys
    float mk = -1e30f;
    #pragma unroll
    for (int j = 0; j < 8; j++)
      #pragma unroll
      for (int jj = 0; jj < 4; jj++) mk = fmaxf(mk, sc[j][jj]);
    mk = fmaxf(mk, __shfl_xor(mk, 16, 64));
    mk = fmaxf(mk, __shfl_xor(mk, 32, 64));
    if (__any(mk > mrun + 8.f)){            // T13: rescale only on real max growth
      float mnew = fmaxf(mrun, mk);
      float f_ = __expf(mrun - mnew);
      mrun = mnew;
      lrun *= f_;
      #pragma unroll
      for (int cf = 0; cf < 4; cf++)
        #pragma unroll
        for (int jj = 0; jj < 4; jj++) o[cf][jj] *= f_;
    }
    float s_ = 0.f;
    #pragma unroll
    for (int j = 0; j < 8; j++)
      #pragma unroll
      for (int jj = 0; jj < 4; jj++){
        sc[j][jj] = __expf(sc[j][jj] - mrun);
        s_ += sc[j][jj];
      }
    s_ += __shfl_xor(s_, 16, 64);
    s_ += __shfl_xor(s_, 32, 64);
    lrun += s_;
    // PV half A
    if (validA){
      #pragma unroll
      for (int kc = 0; kc < 4; kc++){
        int2v pw = { (int)cvtpk(sc[kc][0], sc[kc][1]), (int)cvtpk(sc[kc][2], sc[kc][3]) };
        *reinterpret_cast<int2v*>(&sP[w][q16][kc*16 + g4*4]) = pw;
      }
      v8bf ap[2];
      #pragma unroll
      for (int s2 = 0; s2 < 2; s2++)
        ap[s2] = *reinterpret_cast<const v8bf*>(&sP[w][q16][s2*32 + g4*8]);
      #pragma unroll
      for (int s2 = 0; s2 < 2; s2++){
        v8bf bv[4];
        #pragma unroll
        for (int cf = 0; cf < 4; cf++){
          const short* vsrc = isgA
            ? vgTg + (size_t)bh*4096 + (cf*16 + q16)*64 + s2*32 + g4*8
            : vT + ((size_t)bh*64 + cf*16 + q16)*N_ + kabsA + s2*32 + g4*8;
          bv[cf] = *reinterpret_cast<const v8bf*>(vsrc);
        }
        __builtin_amdgcn_s_setprio(1);
        #pragma unroll
        for (int cf = 0; cf < 4; cf++) o[cf] = mfma16(bv[cf], ap[s2], o[cf]);
        __builtin_amdgcn_s_setprio(0);
      }
    }
    // PV half B
    if (validB){
      #pragma unroll
      for (int kc = 0; kc < 4; kc++){
        int2v pw = { (int)cvtpk(sc[4+kc][0], sc[4+kc][1]), (int)cvtpk(sc[4+kc][2], sc[4+kc][3]) };
        *reinterpret_cast<int2v*>(&sP[w][q16][kc*16 + g4*4]) = pw;
      }
      v8bf ap[2];
      #pragma unroll
      for (int s2 = 0; s2 < 2; s2++)
        ap[s2] = *reinterpret_cast<const v8bf*>(&sP[w][q16][s2*32 + g4*8]);
      #pragma unroll
      for (int s2 = 0; s2 < 2; s2++){
        v8bf bv[4];
        #pragma unroll
        for (int cf = 0; cf < 4; cf++)
          bv[cf] = *reinterpret_cast<const v8bf*>(
              vT + ((size_t)bh*64 + cf*16 + q16)*N_ + kabsB + s2*32 + g4*8);
        __builtin_amdgcn_s_setprio(1);
        #pragma unroll
        for (int cf = 0; cf < 4; cf++) o[cf] = mfma16(bv[cf], ap[s2], o[cf]);
        __builtin_amdgcn_s_setprio(0);
      }
    }
  }
  float inv = 1.0f / lrun;
  int n = qrow0 + q16;
  int i0 = (n >> 7)*2, j0 = (n & 127)*2;
  #pragma unroll
  for (int cf = 0; cf < 4; cf++)
    #pragma unroll
    for (int jj = 0; jj < 4; jj++){
      float val = o[cf][jj] * inv;
      int t_ = h*64 + cf*16 + g4*4 + jj;
      int cc = t_ >> 2, wi = (t_ >> 1) & 1, wj = t_ & 1;
      out[((b*C_ + cc)*IMG + i0 + wi)*IMG + j0 + wj] = val;
    }
}

// ---------------- combine partials, write GPOS rows ------------------------------
__global__ void gattn_combine(const float* __restrict__ gpart, float* __restrict__ out){
  int bh = blockIdx.x; int b = bh / H_, h = bh % H_;
  int t = threadIdx.x;
  int q = t & 63;
  int d = blockIdx.y*4 + (t >> 6);
  if (q >= G_) return;
  const float* pb = gpart + (size_t)bh * 64 * 4224;
  float M = -1e30f;
  for (int p = 0; p < 64; p++) M = fmaxf(M, pb[p*4224 + q]);
  float L = 0.f; float acc = 0.f;
  for (int p = 0; p < 64; p++){
    const float* pp = pb + p*4224;
    float wgt = __expf(pp[q] - M);
    L += pp[64 + q] * wgt;
    acc += pp[128 + d*64 + q] * wgt;
  }
  float invL = 1.0f / L;
  int n = gpos(q);
  int i0 = (n >> 7)*2, j0 = (n & 127)*2;
  int t_ = h*64 + d;
  int cc = t_ >> 2, wi = (t_ >> 1) & 1, wj = t_ & 1;
  out[((b*C_ + cc)*IMG + i0 + wi)*IMG + j0 + wj] = acc * invL;
}

extern "C" void kernel_launch(void* const* d_in, const int* in_sizes, int n_in,
                              void* d_out, int out_size, void* d_ws, size_t ws_size,
                              hipStream_t stream)
{
  (void)in_sizes; (void)n_in; (void)out_size; (void)ws_size;
  const float* x   = (const float*)d_in[0];
  const float* Wq  = (const float*)d_in[1];  const float* bq  = (const float*)d_in[2];
  const float* Wk  = (const float*)d_in[3];  const float* bk  = (const float*)d_in[4];
  const float* Wv  = (const float*)d_in[5];  const float* bv  = (const float*)d_in[6];
  const float* Wqg = (const float*)d_in[7];  const float* bqg = (const float*)d_in[8];
  const float* Wkg = (const float*)d_in[9];  const float* bkg = (const float*)d_in[10];
  const float* Wvg = (const float*)d_in[11]; const float* bvg = (const float*)d_in[12];
  float* out = (float*)d_out;

  short* ws = (short*)d_ws;
  const size_t SZ = (size_t)B_ * N_ * TD;     // 12,582,912 bf16
  short* tokens  = ws;
  short* Wt      = tokens  + SZ;
  short* qgb     = Wt      + (size_t)6*TD*TD;
  short* qbuf    = qgb     + (size_t)128*TD;
  short* kbuf    = qbuf    + SZ;
  short* kgabuf  = kbuf    + SZ;
  short* vT      = kgabuf  + SZ;
  short* vgaT    = vT      + SZ;
  short* kg      = vgaT    + SZ;
  short* vgTg    = kg      + (size_t)12*64*64;
  // gpart (13 MB) aliases tokens: dead once GEMMs + gathers have run.
  float* gpart   = (float*)tokens;

  prep_w<<<dim3(36,6), dim3(256), 0, stream>>>(Wq, Wk, Wv, Wkg, Wvg, Wqg, Wt);
  tokenize<<<dim3(128,4,2), dim3(256), 0, stream>>>(x, tokens);
  gemm_proj<<<dim3(3848), dim3(256), 0, stream>>>(tokens, Wt, bq, bk, bv, bkg, bvg, bqg,
                                                  qbuf, kbuf, vT, kgabuf, vgaT, qgb);
  gather_gkv<<<dim3(12,16), dim3(256), 0, stream>>>(kbuf, vT, kg, vgTg);
  band_attn<<<dim3(1728), dim3(512), 0, stream>>>(qbuf, kbuf, vT, kg, vgTg,
                                                  qgb, kgabuf, vgaT, gpart, out);
  gattn_combine<<<dim3(12,16), dim3(256), 0, stream>>>(gpart, out);
}

// Round 20
// 204.576 us; speedup vs baseline: 1.0144x; 1.0144x over previous
//
#include <hip/hip_runtime.h>

#define DEVI __device__ __forceinline__

typedef __bf16 v8bf __attribute__((ext_vector_type(8)));
typedef float f32x4 __attribute__((ext_vector_type(4)));
typedef int int4v __attribute__((ext_vector_type(4)));
typedef int int2v __attribute__((ext_vector_type(2)));

constexpr int B_  = 2;
constexpr int C_  = 96;
constexpr int IMG = 256;
constexpr int N_  = 16384;   // tokens
constexpr int TD  = 384;
constexpr int H_  = 6;
constexpr int G_  = 50;

DEVI short f2bf(float f){
  unsigned u = __builtin_bit_cast(unsigned, f);
  u = (u + 0x7fffu + ((u >> 16) & 1u)) >> 16;
  return (short)u;
}
DEVI unsigned cvtpk(float lo, float hi){   // dst[15:0]=bf16(lo), dst[31:16]=bf16(hi)
  unsigned r;
  asm("v_cvt_pk_bf16_f32 %0, %1, %2" : "=v"(r) : "v"(lo), "v"(hi));
  return r;
}
DEVI int gpos(int g){ return (16383 * g) / 49; }   // np.linspace(0,16383,50).astype(int32)

DEVI f32x4 mfma16(v8bf a, v8bf b, f32x4 c){
  return __builtin_amdgcn_mfma_f32_16x16x32_bf16(a, b, c, 0, 0, 0);
}

// async global->LDS, 16B per lane; LDS dest is wave-uniform base + lane*16
DEVI void gload16(const void* g, void* l){
  __builtin_amdgcn_global_load_lds((const __attribute__((address_space(1))) void*)g,
                                   (__attribute__((address_space(3))) void*)l, 16, 0, 0);
}

// ---------------- prep: W (k-major f32) -> Wt (n-major bf16) via LDS transpose ---
__global__ __launch_bounds__(256) void prep_w(
    const float* __restrict__ w0, const float* __restrict__ w1,
    const float* __restrict__ w2, const float* __restrict__ w3,
    const float* __restrict__ w4, const float* __restrict__ w5,
    short* __restrict__ Wt){
  __shared__ float sT[64][65];
  int z = blockIdx.y;
  const float* W = z==0 ? w0 : z==1 ? w1 : z==2 ? w2 : z==3 ? w3 : z==4 ? w4 : w5;
  int tile = blockIdx.x;                       // 36 tiles
  int k0 = (tile / 6) * 64, n0 = (tile % 6) * 64;
  int t = threadIdx.x;
  int r = t >> 2, c0 = (t & 3) * 16;
  #pragma unroll
  for (int e = 0; e < 16; e += 4){
    f32x4 v = *reinterpret_cast<const f32x4*>(&W[(size_t)(k0+r)*TD + n0 + c0 + e]);
    #pragma unroll
    for (int i = 0; i < 4; i++) sT[r][c0 + e + i] = v[i];
  }
  __syncthreads();
  int rn = t >> 2, ck0 = (t & 3) * 16;
  short pk[16];
  #pragma unroll
  for (int e = 0; e < 16; e++) pk[e] = f2bf(sT[ck0 + e][rn]);
  short* dst = Wt + (size_t)z*TD*TD + (size_t)(n0+rn)*TD + k0 + ck0;
  *reinterpret_cast<int4v*>(dst)     = *reinterpret_cast<int4v*>(&pk[0]);
  *reinterpret_cast<int4v*>(dst + 8) = *reinterpret_cast<int4v*>(&pk[8]);
}

// ------- tokenize v2: LDS-staged, coalesced x reads ------------------------------
__global__ __launch_bounds__(256) void tokenize(const float* __restrict__ x,
                                                short* __restrict__ tokens){
  __shared__ float sX[24][2][260];
  int p = blockIdx.x, cq = blockIdx.y, b = blockIdx.z;
  int tid = threadIdx.x;
  #pragma unroll
  for (int it = 0; it < 12; it++){
    int u = it*256 + tid;
    int c_l = u >> 7, rem = u & 127, r = rem >> 6, j4 = rem & 63;
    f32x4 v = *reinterpret_cast<const f32x4*>(
        &x[(((size_t)b*C_ + cq*24 + c_l)*IMG + 2*p + r)*IMG + j4*4]);
    *reinterpret_cast<f32x4*>(&sX[c_l][r][j4*4]) = v;
  }
  __syncthreads();
  #pragma unroll
  for (int it = 0; it < 6; it++){
    int v = it*256 + tid;
    int nsj = v / 12, ck = v % 12;
    short o[8];
    #pragma unroll
    for (int e = 0; e < 8; e++){
      int tl = ck*8 + e;
      int c_l = tl >> 2, wi = (tl >> 1) & 1, wj = tl & 1;
      o[e] = f2bf(sX[c_l][wi][2*nsj + wj]);
    }
    *reinterpret_cast<int4v*>(tokens + ((size_t)b*N_ + p*128 + nsj)*TD + cq*96 + ck*8)
        = *reinterpret_cast<int4v*>(o);
  }
}

// ------- 6-way projection GEMM: 128x128, BK=32 dbuf, counted-vmcnt pipeline ------
__global__ __launch_bounds__(256) void gemm_proj(
    const short* __restrict__ A, const short* __restrict__ Wt,
    const float* __restrict__ bq, const float* __restrict__ bk, const float* __restrict__ bv,
    const float* __restrict__ bkg, const float* __restrict__ bvg, const float* __restrict__ bqg,
    short* __restrict__ qbuf, short* __restrict__ kbuf, short* __restrict__ vT,
    short* __restrict__ kgabuf, short* __restrict__ vgaT, short* __restrict__ qgb)
{
  __shared__ short smem[16384];                 // [0,8K): sA dbuf, [8K,16K): sB dbuf
  int lin = blockIdx.x;
  int mt, by, bz;
  if (lin < 3840){
    int id = (lin & 7)*480 + (lin >> 3);
    mt = id / 15; int r15 = id % 15;
    by = r15 % 3; bz = r15 / 3;
  } else {
    int id2 = lin - 3840;
    if (id2 >= 3) return;
    mt = 0; by = id2; bz = 5;
  }
  const float* bias = bz==0 ? bq : bz==1 ? bk : bz==2 ? bv : bz==3 ? bkg : bz==4 ? bvg : bqg;
  const short* Wz = Wt + bz*TD*TD;
  int m0 = mt * 128, n0 = by * 128;
  int tid = threadIdx.x, l = tid & 63, w = tid >> 6;
  int wm = w >> 1, wn = w & 1;
  int q16 = l & 15, g4 = l >> 4;
  bool trans = (bz == 2 || bz == 4);
  bool is_qg = (bz == 5);

  int st_r  = (l >> 2);
  int st_cg = ((l & 3) ^ ((l >> 3) & 3));
  auto STAGE = [&](int kt, int s){
    #pragma unroll
    for (int it = 0; it < 4; it++){
      int ch = w*4 + it;
      int c8 = ch & 7;
      int r_ = c8*16 + st_r;
      const short* src;
      if (ch < 8){
        const short* abase;
        if (is_qg){
          int bq_ = r_ >> 6, qq = r_ & 63;
          abase = A + ((size_t)bq_*N_ + gpos(qq < G_ ? qq : 0))*TD;
        } else {
          abase = A + (size_t)(m0+r_)*TD;
        }
        src = abase + kt*32 + st_cg*8;
      } else {
        src = Wz + (size_t)(n0+r_)*TD + kt*32 + st_cg*8;
      }
      gload16(src, smem + ((ch < 8) ? 0 : 8192) + s*4096 + c8*512);
    }
  };

  int fr = q16;
  int fcg = g4 ^ ((l >> 1) & 3);
  f32x4 acc[4][4] = {};

  STAGE(0, 0);
  if (trans){
    #pragma unroll 2
    for (int t = 0; t < 12; t++){
      int cur = t & 1;
      if (t < 11){ STAGE(t+1, cur ^ 1); asm volatile("s_waitcnt vmcnt(4)" ::: "memory"); }
      else       { asm volatile("s_waitcnt vmcnt(0)" ::: "memory"); }
      __builtin_amdgcn_s_barrier();
      v8bf af[4], bfr[4];
      #pragma unroll
      for (int i = 0; i < 4; i++){
        af[i]  = *reinterpret_cast<const v8bf*>(&smem[       cur*4096 + (wm*64 + i*16 + fr)*32 + fcg*8]);
        bfr[i] = *reinterpret_cast<const v8bf*>(&smem[8192 + cur*4096 + (wn*64 + i*16 + fr)*32 + fcg*8]);
      }
      #pragma unroll
      for (int mi = 0; mi < 4; mi++)
        #pragma unroll
        for (int ni = 0; ni < 4; ni++)
          acc[mi][ni] = mfma16(af[mi], bfr[ni], acc[mi][ni]);
      asm volatile("s_waitcnt lgkmcnt(0)" ::: "memory");
      __builtin_amdgcn_s_barrier();
    }
    // transpose epilogue -> vT/vgaT [bh][64 d][N n]
    short* outT = (bz == 2) ? vT : vgaT;
    #pragma unroll
    for (int mi = 0; mi < 4; mi++){
      int n_base = wm*64 + mi*16 + g4*4;
      #pragma unroll
      for (int ni = 0; ni < 4; ni++){
        int t_local = wn*64 + ni*16 + q16;
        float bc = bias[n0 + t_local];
        short pk[4];
        #pragma unroll
        for (int jj = 0; jj < 4; jj++) pk[jj] = f2bf(acc[mi][ni][jj] + bc);
        int phys = t_local*128 + (((n_base >> 3) ^ (t_local & 15)) << 3) + (n_base & 7);
        *reinterpret_cast<int2v*>(&smem[phys]) = *reinterpret_cast<int2v*>(pk);
      }
    }
    __syncthreads();
    int b = mt >> 7;
    int nb = m0 & 16383;
    #pragma unroll
    for (int p = 0; p < 8; p++){
      int t = p*16 + (tid >> 4);
      int c8 = tid & 15;
      int4v val = *reinterpret_cast<const int4v*>(&smem[t*128 + ((c8 ^ (t & 15)) << 3)]);
      int h = (n0 + t) >> 6, d = (n0 + t) & 63;
      *reinterpret_cast<int4v*>(outT + ((size_t)((b*H_ + h)*64 + d))*N_ + nb + c8*8) = val;
    }
  } else {
    // swapped-operand loop: acc[mi][ni][jj] = C[token mi-blk + q16][td ni-blk + g4*4+jj]
    #pragma unroll 2
    for (int t = 0; t < 12; t++){
      int cur = t & 1;
      if (t < 11){ STAGE(t+1, cur ^ 1); asm volatile("s_waitcnt vmcnt(4)" ::: "memory"); }
      else       { asm volatile("s_waitcnt vmcnt(0)" ::: "memory"); }
      __builtin_amdgcn_s_barrier();
      v8bf af[4], bfr[4];
      #pragma unroll
      for (int i = 0; i < 4; i++){
        af[i]  = *reinterpret_cast<const v8bf*>(&smem[       cur*4096 + (wm*64 + i*16 + fr)*32 + fcg*8]);
        bfr[i] = *reinterpret_cast<const v8bf*>(&smem[8192 + cur*4096 + (wn*64 + i*16 + fr)*32 + fcg*8]);
      }
      #pragma unroll
      for (int mi = 0; mi < 4; mi++)
        #pragma unroll
        for (int ni = 0; ni < 4; ni++)
          acc[mi][ni] = mfma16(bfr[ni], af[mi], acc[mi][ni]);
      asm volatile("s_waitcnt lgkmcnt(0)" ::: "memory");
      __builtin_amdgcn_s_barrier();
    }
    short* out = bz==0 ? qbuf : bz==1 ? kbuf : bz==3 ? kgabuf : qgb;
    float scale = (bz == 0 || bz == 5) ? 0.125f : 1.0f;
    // pack into smem [tok 128][td 128] with 8B-chunk XOR swizzle (2-way, free)
    #pragma unroll
    for (int mi = 0; mi < 4; mi++){
      int tl = wm*64 + mi*16 + q16;
      int x = (tl & 7) << 1;
      #pragma unroll
      for (int ni = 0; ni < 4; ni++){
        int tdl = wn*64 + ni*16 + g4*4;
        f32x4 bvv = *reinterpret_cast<const f32x4*>(&bias[n0 + tdl]);
        short pk[4];
        #pragma unroll
        for (int jj = 0; jj < 4; jj++) pk[jj] = f2bf((acc[mi][ni][jj] + bvv[jj]) * scale);
        int c4 = (tdl >> 2) ^ x;
        *reinterpret_cast<int2v*>(&smem[tl*128 + c4*4]) = *reinterpret_cast<int2v*>(pk);
      }
    }
    __syncthreads();
    #pragma unroll
    for (int p = 0; p < 8; p++){
      int r = p*16 + (tid >> 4);
      int c16 = tid & 15;
      int c4 = (2*c16) ^ ((r & 7) << 1);
      int4v val = *reinterpret_cast<const int4v*>(&smem[r*128 + c4*4]);
      *reinterpret_cast<int4v*>(out + (size_t)(m0 + r)*TD + n0 + c16*8) = val;
    }
  }
}

// ------- per-bh gather of global-token K rows and V^T cols (widened grid) --------
__global__ void gather_gkv(const short* __restrict__ kbuf, const short* __restrict__ vT,
                           short* __restrict__ kg, short* __restrict__ vgTg){
  int bh = blockIdx.x; int s = blockIdx.y;
  int b = bh / H_, h = bh % H_;
  int t = threadIdx.x;
  {                                            // vgTg[bh][64 d][64 g], d-slice
    int d = s*4 + (t >> 6), g = t & 63;
    short val = 0;
    if (g < G_) val = vT[((size_t)bh*64 + d)*N_ + gpos(g)];
    vgTg[(size_t)bh*4096 + d*64 + g] = val;
  }
  {                                            // kg[bh][64 g][64 c], g-slice
    int g = s*4 + (t >> 6), c = t & 63;
    short val = 0;
    if (g < G_) val = kbuf[((size_t)b*N_ + gpos(g))*TD + h*64 + c];
    kg[(size_t)bh*4096 + g*64 + c] = val;
  }
}

// ---- band + global-key attention (blocks 0..1535, exact R12 structure) ----------
// ---- + fused global-token split-K partials (blocks 1536..1727, q-split waves) ---
__global__ __launch_bounds__(512, 4) void band_attn(
    const short* __restrict__ qb, const short* __restrict__ kbuf, const short* __restrict__ vT,
    const short* __restrict__ kg, const short* __restrict__ vgTg,
    const short* __restrict__ qgb, const short* __restrict__ kga, const short* __restrict__ vgaT,
    float* __restrict__ gpart, float* __restrict__ out)
{
  __shared__ short sK[448][64];    // band: K tiles | gattn: per-wave P regions
  __shared__ short sP[8][16][72];  // band: per-wave P[q][kk]
  int lin = blockIdx.x;
  int tid = threadIdx.x, l = tid & 63, w = tid >> 6;
  int g4 = l >> 4, q16 = l & 15;

  if (lin >= 1536){
    // ---------------- fused gattn_partial (q-split: 2 waves per record) ----------
    int gb = lin - 1536;
    int bh2 = gb >> 4, kcg = gb & 15;
    int b2 = bh2 / H_, h2 = bh2 % H_;
    int wr = w >> 1, qh = w & 1;
    int rec = kcg*4 + wr;                      // 0..63 per bh
    short* sp2 = &sK[0][0] + w*2304;           // [32 rows][72 cols] per wave
    v8bf aq2[2][2];
    #pragma unroll
    for (int rf2 = 0; rf2 < 2; rf2++)
      #pragma unroll
      for (int s = 0; s < 2; s++)
        aq2[rf2][s] = *reinterpret_cast<const v8bf*>(
            qgb + (b2*64 + (qh*2+rf2)*16 + q16)*TD + h2*64 + s*32 + g4*8);
    f32x4 o2[2][4] = {};
    float mr[2] = {-1e30f, -1e30f}, lr[2] = {0.f, 0.f};
    int keybase = rec*256;
    for (int st = 0; st < 4; st++){
      int key0 = keybase + st*64;
      v8bf bkf[4][2];
      #pragma unroll
      for (int kcf = 0; kcf < 4; kcf++)
        #pragma unroll
        for (int s = 0; s < 2; s++)
          bkf[kcf][s] = *reinterpret_cast<const v8bf*>(
              kga + ((size_t)b2*N_ + key0 + kcf*16 + q16)*TD + h2*64 + s*32 + g4*8);
      #pragma unroll
      for (int rf2 = 0; rf2 < 2; rf2++){
        f32x4 sc[4] = {};
        #pragma unroll
        for (int kcf = 0; kcf < 4; kcf++){
          sc[kcf] = mfma16(bkf[kcf][0], aq2[rf2][0], sc[kcf]);   // S^T[kk][q]
          sc[kcf] = mfma16(bkf[kcf][1], aq2[rf2][1], sc[kcf]);
        }
        float mk = -1e30f;
        #pragma unroll
        for (int kcf = 0; kcf < 4; kcf++)
          #pragma unroll
          for (int jj = 0; jj < 4; jj++) mk = fmaxf(mk, sc[kcf][jj]);
        mk = fmaxf(mk, __shfl_xor(mk, 16, 64));
        mk = fmaxf(mk, __shfl_xor(mk, 32, 64));
        float mnew = fmaxf(mr[rf2], mk);
        float f_ = __expf(mr[rf2] - mnew);
        mr[rf2] = mnew;
        float s_ = 0.f;
        #pragma unroll
        for (int kcf = 0; kcf < 4; kcf++){
          #pragma unroll
          for (int jj = 0; jj < 4; jj++){
            sc[kcf][jj] = __expf(sc[kcf][jj] - mnew);
            s_ += sc[kcf][jj];
          }
          int2v pw = { (int)cvtpk(sc[kcf][0], sc[kcf][1]), (int)cvtpk(sc[kcf][2], sc[kcf][3]) };
          *reinterpret_cast<int2v*>(&sp2[(rf2*16 + q16)*72 + kcf*16 + g4*4]) = pw;
        }
        s_ += __shfl_xor(s_, 16, 64);
        s_ += __shfl_xor(s_, 32, 64);
        lr[rf2] = lr[rf2]*f_ + s_;
        #pragma unroll
        for (int cf = 0; cf < 4; cf++)
          #pragma unroll
          for (int jj = 0; jj < 4; jj++) o2[rf2][cf][jj] *= f_;
      }
      v8bf bv[4][2];
      #pragma unroll
      for (int cf = 0; cf < 4; cf++)
        #pragma unroll
        for (int s2 = 0; s2 < 2; s2++)
          bv[cf][s2] = *reinterpret_cast<const v8bf*>(
              vgaT + ((size_t)bh2*64 + cf*16 + q16)*N_ + key0 + s2*32 + g4*8);
      #pragma unroll
      for (int rf2 = 0; rf2 < 2; rf2++){
        v8bf ap[2];
        #pragma unroll
        for (int s2 = 0; s2 < 2; s2++)
          ap[s2] = *reinterpret_cast<const v8bf*>(&sp2[(rf2*16 + q16)*72 + s2*32 + g4*8]);
        #pragma unroll
        for (int cf = 0; cf < 4; cf++){
          o2[rf2][cf] = mfma16(bv[cf][0], ap[0], o2[rf2][cf]);
          o2[rf2][cf] = mfma16(bv[cf][1], ap[1], o2[rf2][cf]);
        }
      }
    }
    float* base = gpart + (size_t)(bh2*64 + rec) * 4224;
    #pragma unroll
    for (int rf2 = 0; rf2 < 2; rf2++){
      int rf = qh*2 + rf2;
      if (g4 == 0){ base[rf*16 + q16] = mr[rf2]; base[64 + rf*16 + q16] = lr[rf2]; }
      #pragma unroll
      for (int cf = 0; cf < 4; cf++)
        #pragma unroll
        for (int jj = 0; jj < 4; jj++)
          base[128 + (cf*16 + g4*4 + jj)*64 + rf*16 + q16] = o2[rf2][cf][jj];
    }
    return;
  }

  // ---------------- band path (exact R12/R14 structure) --------------------------
  int id = (lin & 7)*192 + (lin >> 3);
  int c = id & 127;
  int bh = id >> 7; int b = bh / H_, h = bh % H_;
  int cb0 = c*128 - 128;

  #pragma unroll
  for (int it = 0; it < 7; it++){
    int ch = w*7 + it;
    int r = ch*8 + (l>>3);
    int cc = ((l & 7) ^ (l >> 3)) * 8;        // pre-swizzled source colgroup
    const short* src;
    if (ch < 8){
      src = kg + (size_t)bh*4096 + r*64 + cc;
    } else {
      int ka = cb0 + r - 64;
      ka = ka < 0 ? 0 : (ka > N_-1 ? N_-1 : ka);
      src = kbuf + ((size_t)b*N_ + ka)*TD + h*64 + cc;
    }
    gload16(src, &sK[ch*8][0]);
  }

  int qrow0 = c*128 + w*16;
  v8bf aq[2];
  #pragma unroll
  for (int s = 0; s < 2; s++)
    aq[s] = *reinterpret_cast<const v8bf*>(qb + ((size_t)b*N_ + qrow0 + q16)*TD + h*64 + s*32 + g4*8);

  __syncthreads();

  f32x4 o[4] = {};
  float mrun = -1e30f, lrun = 0.f;
  int sbase = w >> 2;
  int i_ = w*16 + q16;

  // QK^T of one 64-key sub-window from sK into sc[4] (swizzled read)
  auto QK = [&](int rbase, f32x4* sc){
    v8bf bkf[4][2];
    #pragma unroll
    for (int kc = 0; kc < 4; kc++)
      #pragma unroll
      for (int s = 0; s < 2; s++)
        bkf[kc][s] = *reinterpret_cast<const v8bf*>(
            &sK[rbase + kc*16 + q16][(((s << 2) | g4) ^ (q16 & 7)) * 8]);
    __builtin_amdgcn_s_setprio(1);
    #pragma unroll
    for (int kc = 0; kc < 4; kc++){
      sc[kc] = mfma16(bkf[kc][0], aq[0], sc[kc]);
      sc[kc] = mfma16(bkf[kc][1], aq[1], sc[kc]);
    }
    __builtin_amdgcn_s_setprio(0);
  };

  for (int ph = 0; ph < 3; ph++){
    int s0bA = (sbase + 2*ph - 1) * 64;     // ph=0: A = global keys
    int s0bB = (sbase + 2*ph) * 64;
    bool isgA = (ph == 0);
    int kabsA = cb0 + s0bA, kabsB = cb0 + s0bB;
    bool validA = isgA || (kabsA >= 0 && kabsA < N_);
    bool validB = (kabsB >= 0 && kabsB < N_);
    if (!validA && !validB) continue;

    f32x4 sc[8];
    const f32x4 negv = {-1e30f, -1e30f, -1e30f, -1e30f};
    #pragma unroll
    for (int j = 0; j < 8; j++) sc[j] = negv;

    if (validA){
      sc[0] = sc[1] = sc[2] = sc[3] = f32x4{0.f, 0.f, 0.f, 0.f};
      QK(isgA ? 0 : 64 + s0bA, &sc[0]);
      if (isgA){
        #pragma unroll
        for (int jj = 0; jj < 4; jj++)
          if (48 + g4*4 + jj >= G_) sc[3][jj] = -1e30f;
      } else {
        bool allv = (s0bA >= w*16 + 15) && (s0bA <= w*16 + 193);
        if (!allv){
          #pragma unroll
          for (int kc = 0; kc < 4; kc++)
            #pragma unroll
            for (int jj = 0; jj < 4; jj++){
              int rel = s0bA + kc*16 + g4*4 + jj - 128 - i_;
              if (rel < -128 || rel > 128) sc[kc][jj] = -1e30f;
            }
        }
      }
    }
    if (validB){
      sc[4] = sc[5] = sc[6] = sc[7] = f32x4{0.f, 0.f, 0.f, 0.f};
      QK(64 + s0bB, &sc[4]);
      bool allv = (s0bB >= w*16 + 15) && (s0bB <= w*16 + 193);
      if (!allv){
        #pragma unroll
        for (int kc = 0; kc < 4; kc++)
          #pragma unroll
          for (int jj = 0; jj < 4; jj++){
            int rel = s0bB + kc*16 + g4*4 + jj - 128 - i_;
            if (rel < -128 || rel > 128) sc[4+kc][jj] = -1e30f;
          }
      }
    }
    // one reduce + (deferred) rescale per 128 keys
    float mk = -1e30f;
    #pragma unroll
    for (int j = 0; j < 8; j++)
      #pragma unroll
      for (int jj = 0; jj < 4; jj++) mk = fmaxf(mk, sc[j][jj]);
    mk = fmaxf(mk, __shfl_xor(mk, 16, 64));
    mk = fmaxf(mk, __shfl_xor(mk, 32, 64));
    if (__any(mk > mrun + 8.f)){            // T13: rescale only on real max growth
      float mnew = fmaxf(mrun, mk);
      float f_ = __expf(mrun - mnew);
      mrun = mnew;
      lrun *= f_;
      #pragma unroll
      for (int cf = 0; cf < 4; cf++)
        #pragma unroll
        for (int jj = 0; jj < 4; jj++) o[cf][jj] *= f_;
    }
    float s_ = 0.f;
    #pragma unroll
    for (int j = 0; j < 8; j++)
      #pragma unroll
      for (int jj = 0; jj < 4; jj++){
        sc[j][jj] = __expf(sc[j][jj] - mrun);
        s_ += sc[j][jj];
      }
    s_ += __shfl_xor(s_, 16, 64);
    s_ += __shfl_xor(s_, 32, 64);
    lrun += s_;
    // PV half A
    if (validA){
      #pragma unroll
      for (int kc = 0; kc < 4; kc++){
        int2v pw = { (int)cvtpk(sc[kc][0], sc[kc][1]), (int)cvtpk(sc[kc][2], sc[kc][3]) };
        *reinterpret_cast<int2v*>(&sP[w][q16][kc*16 + g4*4]) = pw;
      }
      v8bf ap[2];
      #pragma unroll
      for (int s2 = 0; s2 < 2; s2++)
        ap[s2] = *reinterpret_cast<const v8bf*>(&sP[w][q16][s2*32 + g4*8]);
      #pragma unroll
      for (int s2 = 0; s2 < 2; s2++){
        v8bf bv[4];
        #pragma unroll
        for (int cf = 0; cf < 4; cf++){
          const short* vsrc = isgA
            ? vgTg + (size_t)bh*4096 + (cf*16 + q16)*64 + s2*32 + g4*8
            : vT + ((size_t)bh*64 + cf*16 + q16)*N_ + kabsA + s2*32 + g4*8;
          bv[cf] = *reinterpret_cast<const v8bf*>(vsrc);
        }
        __builtin_amdgcn_s_setprio(1);
        #pragma unroll
        for (int cf = 0; cf < 4; cf++) o[cf] = mfma16(bv[cf], ap[s2], o[cf]);
        __builtin_amdgcn_s_setprio(0);
      }
    }
    // PV half B
    if (validB){
      #pragma unroll
      for (int kc = 0; kc < 4; kc++){
        int2v pw = { (int)cvtpk(sc[4+kc][0], sc[4+kc][1]), (int)cvtpk(sc[4+kc][2], sc[4+kc][3]) };
        *reinterpret_cast<int2v*>(&sP[w][q16][kc*16 + g4*4]) = pw;
      }
      v8bf ap[2];
      #pragma unroll
      for (int s2 = 0; s2 < 2; s2++)
        ap[s2] = *reinterpret_cast<const v8bf*>(&sP[w][q16][s2*32 + g4*8]);
      #pragma unroll
      for (int s2 = 0; s2 < 2; s2++){
        v8bf bv[4];
        #pragma unroll
        for (int cf = 0; cf < 4; cf++)
          bv[cf] = *reinterpret_cast<const v8bf*>(
              vT + ((size_t)bh*64 + cf*16 + q16)*N_ + kabsB + s2*32 + g4*8);
        __builtin_amdgcn_s_setprio(1);
        #pragma unroll
        for (int cf = 0; cf < 4; cf++) o[cf] = mfma16(bv[cf], ap[s2], o[cf]);
        __builtin_amdgcn_s_setprio(0);
      }
    }
  }
  float inv = 1.0f / lrun;
  int n = qrow0 + q16;
  int i0 = (n >> 7)*2, j0 = (n & 127)*2;
  #pragma unroll
  for (int cf = 0; cf < 4; cf++)
    #pragma unroll
    for (int jj = 0; jj < 4; jj++){
      float val = o[cf][jj] * inv;
      int t_ = h*64 + cf*16 + g4*4 + jj;
      int cc = t_ >> 2, wi = (t_ >> 1) & 1, wj = t_ & 1;
      out[((b*C_ + cc)*IMG + i0 + wi)*IMG + j0 + wj] = val;
    }
}

// ---------------- combine partials, write GPOS rows ------------------------------
__global__ void gattn_combine(const float* __restrict__ gpart, float* __restrict__ out){
  int bh = blockIdx.x; int b = bh / H_, h = bh % H_;
  int t = threadIdx.x;
  int q = t & 63;
  int d = blockIdx.y*4 + (t >> 6);
  if (q >= G_) return;
  const float* pb = gpart + (size_t)bh * 64 * 4224;
  float M = -1e30f;
  for (int p = 0; p < 64; p++) M = fmaxf(M, pb[p*4224 + q]);
  float L = 0.f; float acc = 0.f;
  for (int p = 0; p < 64; p++){
    const float* pp = pb + p*4224;
    float wgt = __expf(pp[q] - M);
    L += pp[64 + q] * wgt;
    acc += pp[128 + d*64 + q] * wgt;
  }
  float invL = 1.0f / L;
  int n = gpos(q);
  int i0 = (n >> 7)*2, j0 = (n & 127)*2;
  int t_ = h*64 + d;
  int cc = t_ >> 2, wi = (t_ >> 1) & 1, wj = t_ & 1;
  out[((b*C_ + cc)*IMG + i0 + wi)*IMG + j0 + wj] = acc * invL;
}

extern "C" void kernel_launch(void* const* d_in, const int* in_sizes, int n_in,
                              void* d_out, int out_size, void* d_ws, size_t ws_size,
                              hipStream_t stream)
{
  (void)in_sizes; (void)n_in; (void)out_size; (void)ws_size;
  const float* x   = (const float*)d_in[0];
  const float* Wq  = (const float*)d_in[1];  const float* bq  = (const float*)d_in[2];
  const float* Wk  = (const float*)d_in[3];  const float* bk  = (const float*)d_in[4];
  const float* Wv  = (const float*)d_in[5];  const float* bv  = (const float*)d_in[6];
  const float* Wqg = (const float*)d_in[7];  const float* bqg = (const float*)d_in[8];
  const float* Wkg = (const float*)d_in[9];  const float* bkg = (const float*)d_in[10];
  const float* Wvg = (const float*)d_in[11]; const float* bvg = (const float*)d_in[12];
  float* out = (float*)d_out;

  short* ws = (short*)d_ws;
  const size_t SZ = (size_t)B_ * N_ * TD;     // 12,582,912 bf16
  short* tokens  = ws;
  short* Wt      = tokens  + SZ;
  short* qgb     = Wt      + (size_t)6*TD*TD;
  short* qbuf    = qgb     + (size_t)128*TD;
  short* kbuf    = qbuf    + SZ;
  short* kgabuf  = kbuf    + SZ;
  short* vT      = kgabuf  + SZ;
  short* vgaT    = vT      + SZ;
  short* kg      = vgaT    + SZ;
  short* vgTg    = kg      + (size_t)12*64*64;
  // gpart (13 MB) aliases tokens: dead once GEMMs + gathers have run.
  float* gpart   = (float*)tokens;

  prep_w<<<dim3(36,6), dim3(256), 0, stream>>>(Wq, Wk, Wv, Wkg, Wvg, Wqg, Wt);
  tokenize<<<dim3(128,4,2), dim3(256), 0, stream>>>(x, tokens);
  gemm_proj<<<dim3(3848), dim3(256), 0, stream>>>(tokens, Wt, bq, bk, bv, bkg, bvg, bqg,
                                                  qbuf, kbuf, vT, kgabuf, vgaT, qgb);
  gather_gkv<<<dim3(12,16), dim3(256), 0, stream>>>(kbuf, vT, kg, vgTg);
  band_attn<<<dim3(1728), dim3(512), 0, stream>>>(qbuf, kbuf, vT, kg, vgTg,
                                                  qgb, kgabuf, vgaT, gpart, out);
  gattn_combine<<<dim3(12,16), dim3(256), 0, stream>>>(gpart, out);
}